// Round 12
// baseline (2657.448 us; speedup 1.0000x reference)
//
#include <hip/hip_runtime.h>

// LSTM decoder B=64,S=512,D=512,H=512,L=2 — Round 12: R11 + overlapped exchange.
// h exchange: tagged words (epoch<<16 | bf16) in 8-deep u32 buffers (sc1/L3).
// Flag = hint + anti-dep bound, posted right after the GEMM barrier (reads done),
// so its propagation overlaps producer cell math + h stores. No drains.
// Consumers: poll hint (all waves), batched sc1 tag-validated loads, batch retry.
// Compute identical to R11: K-split 8 waves, weights pinned in 64 VGPRs.

#define NB 64
#define NS 512
#define ND 512
#define NH 512

typedef __attribute__((ext_vector_type(8))) short short8;
typedef __attribute__((ext_vector_type(4))) float f32x4;
typedef __attribute__((ext_vector_type(4))) unsigned int u32x4;

// ---- ws layout (bytes) ----
#define WPK_OFF   0                  // 8,388,608
#define HT0_OFF   8388608            // 8 bufs * 32768 u32 = 1MB
#define HT1_OFF   9437184            // 1MB
#define FLAGS_OFF 10485760           // 256 u32
#define WPK_ELEMS_PER_ROLE (128 * 32 * 512)

__device__ __forceinline__ unsigned int pack2bf(float a, float b) {
    unsigned int ua = __builtin_bit_cast(unsigned int, a);
    unsigned int ub = __builtin_bit_cast(unsigned int, b);
    ua += 0x7fffu + ((ua >> 16) & 1u);   // RNE
    ub += 0x7fffu + ((ub >> 16) & 1u);
    return (ua >> 16) | (ub & 0xffff0000u);
}
__device__ __forceinline__ unsigned short bf16r(float a) {
    unsigned int ua = __builtin_bit_cast(unsigned int, a);
    ua += 0x7fffu + ((ua >> 16) & 1u);
    return (unsigned short)(ua >> 16);
}

__device__ __forceinline__ void st_h32(unsigned int* p, unsigned int v) {
    __hip_atomic_store(p, v, __ATOMIC_RELAXED, __HIP_MEMORY_SCOPE_AGENT);
}
__device__ __forceinline__ unsigned int ld_flag(const unsigned int* p) {
    return __hip_atomic_load(p, __ATOMIC_RELAXED, __HIP_MEMORY_SCOPE_AGENT);
}
__device__ __forceinline__ void st_flag(unsigned int* p, unsigned int v) {
    __hip_atomic_store(p, v, __ATOMIC_RELAXED, __HIP_MEMORY_SCOPE_AGENT);
}

__device__ __forceinline__ bool tag8_ok(const u32x4& a, const u32x4& b, unsigned int T) {
    unsigned int m = ((a.x >> 16) ^ T) | ((a.y >> 16) ^ T)
                   | ((a.z >> 16) ^ T) | ((a.w >> 16) ^ T)
                   | ((b.x >> 16) ^ T) | ((b.y >> 16) ^ T)
                   | ((b.z >> 16) ^ T) | ((b.w >> 16) ^ T);
    return m == 0;
}
__device__ __forceinline__ u32x4 pack8(const u32x4& a, const u32x4& b) {
    u32x4 r;
    r.x = (a.x & 0xFFFFu) | (a.y << 16);
    r.y = (a.z & 0xFFFFu) | (a.w << 16);
    r.z = (b.x & 0xFFFFu) | (b.y << 16);
    r.w = (b.z & 0xFFFFu) | (b.w << 16);
    return r;
}

// 2 slots (2x32B) sc1 load, single waitcnt
__device__ __forceinline__ void load2(const unsigned int* q0, const unsigned int* q1,
                                      u32x4& a0, u32x4& b0, u32x4& a1, u32x4& b1) {
    asm volatile(
        "global_load_dwordx4 %0, %4, off sc0 sc1\n\t"
        "global_load_dwordx4 %1, %4, off offset:16 sc0 sc1\n\t"
        "global_load_dwordx4 %2, %5, off sc0 sc1\n\t"
        "global_load_dwordx4 %3, %5, off offset:16 sc0 sc1\n\t"
        "s_waitcnt vmcnt(0)"
        : "=&v"(a0), "=&v"(b0), "=&v"(a1), "=&v"(b1)
        : "v"(q0), "v"(q1) : "memory");
    __builtin_amdgcn_sched_barrier(0);
}

// Repack weights into MFMA B-fragment order:
// fragment (r, nt, k0i), lane l, elem j: B[k][n], n = nt*16+(l&15), k = k0i*32+(l>>4)*8+j
__global__ void prep_weights_k(const float* __restrict__ W_ih,
                               const float* __restrict__ W_hh,
                               unsigned int* __restrict__ wpk_u32) {
    long long gid = (long long)blockIdx.x * blockDim.x + threadIdx.x; // 524288
    int l   = (int)(gid & 63);
    int k0i = (int)((gid >> 6) & 31);
    int nt  = (int)((gid >> 11) & 127);
    int r   = (int)(gid >> 18);
    int n = nt * 16 + (l & 15);
    int k = k0i * 32 + ((l >> 4) << 3);
    const float* src;
    if (k < 512) src = W_ih + ((long long)r * 2048 + n) * 512 + k;
    else         src = W_hh + ((long long)r * 2048 + n) * 512 + (k - 512);
    uint4 v;
    v.x = pack2bf(src[0], src[1]);
    v.y = pack2bf(src[2], src[3]);
    v.z = pack2bf(src[4], src[5]);
    v.w = pack2bf(src[6], src[7]);
    ((uint4*)wpk_u32)[gid] = v;
}

// Clear ALL tagged buffers every call (kills stale tags across graph replays);
// h_{-1} = enc_h with tag 0 into buf 7 of both arrays; zero flags.
__global__ void prep_state_k(const float* __restrict__ eh,
                             unsigned int* __restrict__ ht0,
                             unsigned int* __restrict__ ht1,
                             unsigned int* __restrict__ flags) {
    int gid = blockIdx.x * blockDim.x + threadIdx.x;  // 262144
    if (gid < 262144) {
        int buf = gid >> 15, idx = gid & 32767;
        unsigned int v = (buf == 7) ? (unsigned int)bf16r(eh[idx]) : 0u;
        ht0[gid] = v;
        ht1[gid] = v;
    }
    if (gid < 256) flags[gid] = 0;
}

__global__ __launch_bounds__(512, 1)
void lstm_persist_k(const float* __restrict__ input,
                    const float* __restrict__ enc_c,
                    const float* __restrict__ b_ih,
                    const float* __restrict__ b_hh,
                    const unsigned short* __restrict__ wpk,
                    unsigned int* __restrict__ ht0,
                    unsigned int* __restrict__ ht1,
                    float* __restrict__ out,
                    unsigned int* __restrict__ flags) {
    __shared__ alignas(16) unsigned char smem[32768];   // A tile (fragment-packed)
    __shared__ float Gp[8][16][17];                     // partial gates per wave
    const int bid  = blockIdx.x;
    const int role = bid >> 7;             // 0: layer0(i), 1: layer1(i-1)
    const int lb   = bid & 127;
    const int ms   = lb >> 5;              // batch block 0..3 (sync group)
    const int us   = lb & 31;              // unit block 0..31
    const int m0   = ms << 4;
    const int tid  = threadIdx.x;
    const int lane = tid & 63;
    const int w    = tid >> 6;             // wave 0..7
    const int g    = __builtin_amdgcn_readfirstlane(w & 3);   // gate
    const int kh   = __builtin_amdgcn_readfirstlane(w >> 2);  // K-half

    const unsigned short* wp = wpk + (long long)role * WPK_ELEMS_PER_ROLE
                             + (long long)(g * 32 + us) * (32 * 512)
                             + (long long)kh * 16 * 512;
    const unsigned char* aBase = smem + kh * 16384;

    // ---- pin this wave's 16 B-fragments in registers (once) ----
    short8 wreg[16];
    #pragma unroll
    for (int j = 0; j < 16; ++j)
        wreg[j] = *(const short8*)(wp + j * 512 + lane * 8);
    #pragma unroll
    for (int j = 0; j < 16; ++j)
        asm volatile("" : "+v"(wreg[j]));

    unsigned int* myflag   = flags + (ms << 6) + (role << 5) + us;
    const unsigned int* gf = flags + (ms << 6) + lane;

    // ---- cell state + biases (threads 0..255 own the 256 cells) ----
    const int m_l = (tid >> 4) & 15, u_l = tid & 15;
    const int bcell = m0 + m_l;
    const int ucell = us * 16 + u_l;
    float cReg = 0.f, bias_i = 0.f, bias_f = 0.f, bias_g = 0.f, bias_o = 0.f;
    if (tid < 256) {
        cReg = enc_c[bcell * NH + ucell];
        const long long br = (long long)role * 2048;
        bias_i = b_ih[br + 0 * 512 + ucell] + b_hh[br + 0 * 512 + ucell];
        bias_f = b_ih[br + 1 * 512 + ucell] + b_hh[br + 1 * 512 + ucell];
        bias_g = b_ih[br + 2 * 512 + ucell] + b_hh[br + 2 * 512 + ucell];
        bias_o = b_ih[br + 3 * 512 + ucell] + b_hh[br + 3 * 512 + ucell];
    }

    // staging geometry: thread's h-part slots are {1024+tid, 1536+tid};
    // role1 additionally x-part slots {tid, 512+tid}.
    const int srow  = tid & 15;
    const int skoff = ((tid >> 4) & 3) << 3;
    const int w32   = w << 5;
    const int rowoff = (m0 + srow) * 512 + w32 + skoff;   // u32 offset in h buffers

    // ---- role0: prefetch x(0) into registers ----
    float4 xp[4];
    if (role == 0) {
        #pragma unroll
        for (int j2 = 0; j2 < 2; ++j2) {
            int sid = j2 * 512 + tid;
            int k = (sid >> 6) * 32 + skoff;
            const float* s = input + (long long)(m0 + srow) * (NS * ND) + k;
            xp[2 * j2]     = *(const float4*)s;
            xp[2 * j2 + 1] = *(const float4*)(s + 4);
        }
    }

    for (int i = 0; i <= NS; ++i) {
        const bool active = (role == 0) ? (i < NS) : (i >= 1);

        // ---- A: role0 pre-poll x staging (regs -> LDS x-region) ----
        if (role == 0 && i < NS) {
            #pragma unroll
            for (int j2 = 0; j2 < 2; ++j2) {
                int sid = j2 * 512 + tid;
                float4 lo = xp[2 * j2], hi = xp[2 * j2 + 1];
                uint4 val;
                val.x = pack2bf(lo.x, lo.y);
                val.y = pack2bf(lo.z, lo.w);
                val.z = pack2bf(hi.x, hi.y);
                val.w = pack2bf(hi.z, hi.w);
                *(uint4*)(smem + sid * 16) = val;
            }
        }

        // ---- B: hint poll (ALL waves poll -> no barrier needed after) ----
        if (i > 0) {
            unsigned int thr;
            if (role == 0)
                thr = (lane < 32) ? (unsigned int)i
                                  : (unsigned int)(i >= 2 ? i - 2 : 0);
            else
                thr = (unsigned int)i;
            for (;;) {
                unsigned int v = ld_flag(gf);
                if (__ballot(v >= thr) == 0xFFFFFFFFFFFFFFFFULL) break;
                __builtin_amdgcn_s_sleep(1);
            }
        }

        if (active) {
            // ---- C: tagged staging (batched loads + batch retry) ----
            if (role == 0) {
                // h-part = h0_{i-1}, tag i
                const unsigned int* hb = ht0 + (((i - 1) & 7) << 15);
                const unsigned int T = (unsigned int)i;
                const unsigned int* q0 = hb + rowoff;
                const unsigned int* q1 = q0 + 256;
                u32x4 a0, b0, a1, b1;
                for (;;) {
                    load2(q0, q1, a0, b0, a1, b1);
                    if (tag8_ok(a0, b0, T) && tag8_ok(a1, b1, T)) break;
                }
                *(u32x4*)(smem + (1024 + tid) * 16) = pack8(a0, b0);
                *(u32x4*)(smem + (1536 + tid) * 16) = pack8(a1, b1);
            } else {
                // x-part = h0_{i-1} (tag i); h-part = h1_{i-2} (tag i-1)
                const unsigned int* xb = ht0 + (((i - 1) & 7) << 15);
                const unsigned int* hb = ht1 + (((i - 2) & 7) << 15);
                const unsigned int Tx = (unsigned int)i;
                const unsigned int Th = (unsigned int)(i - 1);
                const unsigned int* px0 = xb + rowoff;
                const unsigned int* px1 = px0 + 256;
                const unsigned int* ph0 = hb + rowoff;
                const unsigned int* ph1 = ph0 + 256;
                u32x4 xa0, xc0, xa1, xc1, ha0, hc0, ha1, hc1;
                for (;;) {
                    load2(px0, px1, xa0, xc0, xa1, xc1);
                    load2(ph0, ph1, ha0, hc0, ha1, hc1);
                    if (tag8_ok(xa0, xc0, Tx) && tag8_ok(xa1, xc1, Tx) &&
                        tag8_ok(ha0, hc0, Th) && tag8_ok(ha1, hc1, Th)) break;
                }
                *(u32x4*)(smem + (tid) * 16)        = pack8(xa0, xc0);
                *(u32x4*)(smem + (512 + tid) * 16)  = pack8(xa1, xc1);
                *(u32x4*)(smem + (1024 + tid) * 16) = pack8(ha0, hc0);
                *(u32x4*)(smem + (1536 + tid) * 16) = pack8(ha1, hc1);
            }
            __syncthreads();    // A staged

            // ---- GEMM: wave (g,kh) -> 16 MFMAs, B from registers ----
            f32x4 acc0 = {0.f,0.f,0.f,0.f}, acc1 = {0.f,0.f,0.f,0.f};
            #pragma unroll
            for (int j = 0; j < 16; j += 2) {
                short8 a0 = *(const short8*)(aBase + (j + 0) * 1024 + lane * 16);
                short8 a1 = *(const short8*)(aBase + (j + 1) * 1024 + lane * 16);
                acc0 = __builtin_amdgcn_mfma_f32_16x16x32_bf16(a0, wreg[j + 0], acc0, 0, 0, 0);
                acc1 = __builtin_amdgcn_mfma_f32_16x16x32_bf16(a1, wreg[j + 1], acc1, 0, 0, 0);
            }
            f32x4 accS = acc0 + acc1;
            {
                int u_g  = lane & 15;
                int mrow = (lane >> 4) * 4;
                #pragma unroll
                for (int r = 0; r < 4; ++r)
                    Gp[w][mrow + r][u_g] = accS[r];
            }
            __syncthreads();    // Gp ready; ALL reads of this step done

            // ---- flag post EARLY: reads done; writes imminent (hint) ----
            if (tid == 0) st_flag(myflag, (unsigned int)(i + 1));

            // ---- role0: prefetch x(i+1); latency hides under cell ----
            if (role == 0 && i + 1 < NS) {
                #pragma unroll
                for (int j2 = 0; j2 < 2; ++j2) {
                    int sid = j2 * 512 + tid;
                    int k = (sid >> 6) * 32 + skoff;
                    const float* s = input + (long long)(m0 + srow) * (NS * ND)
                                           + (long long)(i + 1) * ND + k;
                    xp[2 * j2]     = *(const float4*)s;
                    xp[2 * j2 + 1] = *(const float4*)(s + 4);
                }
            }

            // ---- fused LSTM cell: threads 0..255, tagged h store ----
            if (tid < 256) {
                float gi = Gp[0][m_l][u_l] + Gp[4][m_l][u_l] + bias_i;
                float gf = Gp[1][m_l][u_l] + Gp[5][m_l][u_l] + bias_f;
                float gg = Gp[2][m_l][u_l] + Gp[6][m_l][u_l] + bias_g;
                float go = Gp[3][m_l][u_l] + Gp[7][m_l][u_l] + bias_o;
                float ii = 1.f / (1.f + expf(-gi));
                float ff = 1.f / (1.f + expf(-gf));
                float gv = tanhf(gg);
                float oo = 1.f / (1.f + expf(-go));
                cReg = ff * cReg + ii * gv;
                float hn = oo * tanhf(cReg);
                unsigned short hb16 = bf16r(hn);

                if (role == 0) {
                    unsigned int* hbuf = ht0 + ((i & 7) << 15);
                    st_h32(hbuf + bcell * 512 + ucell,
                           ((unsigned int)(i + 1) << 16) | hb16);
                } else {
                    unsigned int* hbuf = ht1 + (((i - 1) & 7) << 15);
                    st_h32(hbuf + bcell * 512 + ucell,
                           ((unsigned int)i << 16) | hb16);
                    int s = i - 1;
                    out[(long long)bcell * (NS * NH) + (long long)s * NH + ucell] = hn;
                    if (i == NS) {
                        float* dst = out + (long long)NB * NS * NH;
                        dst[bcell * NH + ucell] = hn;
                        dst[NB * NH + bcell * NH + ucell] = cReg;
                    }
                }
            }
            // no trailing barrier: next iter's smem writes are ordered after the
            // GEMM barrier in every thread's program order; Gp rewrites happen
            // only after the next staging barrier.
        } else {
            if (tid == 0) st_flag(myflag, (unsigned int)(i + 1));
        }
    }
}

extern "C" void kernel_launch(void* const* d_in, const int* in_sizes, int n_in,
                              void* d_out, int out_size, void* d_ws, size_t ws_size,
                              hipStream_t stream) {
    const float* input = (const float*)d_in[0];
    const float* enc_h = (const float*)d_in[1];
    const float* enc_c = (const float*)d_in[2];
    const float* W_ih  = (const float*)d_in[3];
    const float* W_hh  = (const float*)d_in[4];
    const float* b_ih  = (const float*)d_in[5];
    const float* b_hh  = (const float*)d_in[6];
    float* out = (float*)d_out;
    unsigned char* ws = (unsigned char*)d_ws;

    unsigned short* wpk   = (unsigned short*)(ws + WPK_OFF);
    unsigned int*   ht0   = (unsigned int*)(ws + HT0_OFF);
    unsigned int*   ht1   = (unsigned int*)(ws + HT1_OFF);
    unsigned int*   flags = (unsigned int*)(ws + FLAGS_OFF);

    prep_weights_k<<<2048, 256, 0, stream>>>(W_ih, W_hh, (unsigned int*)wpk);
    prep_state_k<<<1024, 256, 0, stream>>>(enc_h, ht0, ht1, flags);
    lstm_persist_k<<<256, 512, 0, stream>>>(input, enc_c, b_ih, b_hh, wpk,
                                            ht0, ht1, out, flags);
}